// Round 10
// baseline (96.820 us; speedup 1.0000x reference)
//
#include <hip/hip_runtime.h>

// Fixed sizes
#define G_    32
#define O_    16
#define OUTD  128
#define DS_   64      // scalar half / SDIM
#define VC    48      // V*3
#define M_    2048    // rows per graph
#define ROWS  128     // rows per chunk block
#define CPG   16      // chunks per graph (2048/128)
#define XP    136     // xT / cT pitch in bf16 elems (rows 16B-aligned: 272B)
#define XPD   68      // pitch in dwords
#define WVP   72      // wv_s pitch in bf16
#define YLP   132     // y_lds pitch in f32 (mult of 4 for float4 reads)

typedef __attribute__((ext_vector_type(8))) short short8;
typedef __attribute__((ext_vector_type(4))) float f32x4;

__device__ __forceinline__ unsigned short f2bf(float f) {
  unsigned u = __float_as_uint(f);
  return (unsigned short)((u + 0x7FFFu + ((u >> 16) & 1u)) >> 16);
}
__device__ __forceinline__ float bf2f(short v) {
  return __uint_as_float(((unsigned)(unsigned short)v) << 16);
}

// ---------------------------------------------------------------------------
// K0: transpose+convert x -> bf16 xTg (once); column sums accumulated
//   directly into ysum[g][k] via HW f32 atomics (it-0 y is rank-1).
// ---------------------------------------------------------------------------
__global__ __launch_bounds__(256) void stage_x(
    const float* __restrict__ x, short* __restrict__ xTg,
    float* __restrict__ ysum)
{
  const int blk = blockIdx.x, g = blk >> 4;
  const int t = threadIdx.x;
  __shared__ short xT[128 * XP];

  const float* xg = x + (size_t)blk * (ROWS * OUTD);
  {
    const int rg = t >> 2, qc = t & 3;
    const float4* r0q = (const float4*)(xg + (size_t)(2 * rg) * OUTD + qc * 32);
    const float4* r1q = (const float4*)(xg + (size_t)(2 * rg + 1) * OUTD + qc * 32);
    float4 a0 = r0q[0], a1 = r0q[1], a2 = r0q[2], a3 = r0q[3],
           a4 = r0q[4], a5 = r0q[5], a6 = r0q[6], a7 = r0q[7];
    float4 b0 = r1q[0], b1 = r1q[1], b2 = r1q[2], b3 = r1q[3],
           b4 = r1q[4], b5 = r1q[5], b6 = r1q[6], b7 = r1q[7];
    unsigned* xTd = (unsigned*)xT;
    const int cb = qc * 32;
#define STAGE4(S, A, B)                                                        \
    xTd[(cb + S*4 + 0) * XPD + rg] = (unsigned)f2bf(A.x) | ((unsigned)f2bf(B.x) << 16); \
    xTd[(cb + S*4 + 1) * XPD + rg] = (unsigned)f2bf(A.y) | ((unsigned)f2bf(B.y) << 16); \
    xTd[(cb + S*4 + 2) * XPD + rg] = (unsigned)f2bf(A.z) | ((unsigned)f2bf(B.z) << 16); \
    xTd[(cb + S*4 + 3) * XPD + rg] = (unsigned)f2bf(A.w) | ((unsigned)f2bf(B.w) << 16);
    STAGE4(0, a0, b0) STAGE4(1, a1, b1) STAGE4(2, a2, b2) STAGE4(3, a3, b3)
    STAGE4(4, a4, b4) STAGE4(5, a5, b5) STAGE4(6, a6, b6) STAGE4(7, a7, b7)
#undef STAGE4
  }
  __syncthreads();

  // writeout: xT LDS -> xTg global, contiguous [k][128] bf16
  {
    short8* dst = (short8*)(xTg + (size_t)blk * (128 * 128));
#pragma unroll
    for (int i = 0; i < 8; ++i) {
      int c = i * 256 + t;
      dst[c] = *(const short8*)&xT[(c >> 4) * XP + (c & 15) * 8];
    }
  }
  // column sums -> atomic accumulate into ysum[g][k]
  {
    const int k = t >> 1, half = t & 1;
    float s = 0.f;
#pragma unroll
    for (int j = 0; j < 8; ++j) {
      short8 v = *(const short8*)&xT[k * XP + half * 64 + j * 8];
#pragma unroll
      for (int e = 0; e < 8; ++e) s += bf2f(v[e]);
    }
    s += __shfl_xor(s, 1);
    if (half == 0) unsafeAtomicAdd(&ysum[(size_t)g * 128 + k], s);
  }
}

// ---------------------------------------------------------------------------
// capsA_t<LAST>: stage bf16 xTg -> LDS, GEMM1 logits + softmax -> cT,
//   GEMM2 -> atomicAdd into y[g][o][k].  LAST: cp + routed via atomicAdd.
// ---------------------------------------------------------------------------
template<int LAST>
__global__ __launch_bounds__(256) void capsA_t(
    const short* __restrict__ xTg, const float* __restrict__ xv,
    const float* __restrict__ wvacc, float* __restrict__ y_out,
    float* __restrict__ routed)
{
  const int blk = blockIdx.x, g = blk >> 4, chunk = blk & 15;
  const int t = threadIdx.x, lane = t & 63, w = t >> 6;

  __shared__ short xT[128 * XP];      // 34816 B
  __shared__ short cT[O_ * XP];       // 4352 B
  __shared__ short wv_s[O_ * WVP];    // 2304 B
  __shared__ float cp_s[16][17];      // 1088 B
  __shared__ float xv_s[16 * VC];     // 3072 B
  __shared__ float y_lds[16 * YLP];   // 8448 B

  // ---- stage xTg -> xT (pure reg copy, 16B/lane) ----
  {
    const short8* src = (const short8*)(xTg + (size_t)blk * (128 * 128));
#pragma unroll
    for (int i = 0; i < 8; ++i) {
      int c = i * 256 + t;
      *(short8*)&xT[(c >> 4) * XP + (c & 15) * 8] = src[c];
    }
  }
  {
    const float* wvg = wvacc + (size_t)g * O_ * DS_;
    for (int i = t; i < O_ * DS_; i += 256) {
      int o = i >> 6, k = i & 63;
      wv_s[o * WVP + k] = (short)f2bf(wvg[i]);
    }
  }
  if (LAST) {
    const float* xvg = xv + (size_t)(g * 256 + chunk * 16) * VC;
    for (int i = t; i < 16 * VC; i += 256) xv_s[i] = xvg[i];
  }
  __syncthreads();

  // ---- GEMM1 + softmax -> cT (+ registers for cp) ----
  {
    const int mrow = lane & 15, gq = lane >> 4;
    float c_fA[4], c_fB[4];
#define LOGIT_TILE(NT2, CF)                                                    \
    {                                                                          \
      const int nt = 2 * w + NT2;                                              \
      const int mcol = nt * 16 + mrow;                                         \
      f32x4 acc = {0.f, 0.f, 0.f, 0.f};                                        \
      _Pragma("unroll")                                                        \
      for (int ks = 0; ks < 2; ++ks) {                                         \
        short8 af = *(const short8*)&wv_s[mrow * WVP + ks * 32 + gq * 8];      \
        short8 bf;                                                             \
        _Pragma("unroll")                                                      \
        for (int e = 0; e < 8; ++e)                                            \
          bf[e] = xT[(ks * 32 + gq * 8 + e) * XP + mcol];                      \
        acc = __builtin_amdgcn_mfma_f32_16x16x32_bf16(af, bf, acc, 0, 0, 0);   \
      }                                                                        \
      float mx = fmaxf(fmaxf(acc[0], acc[1]), fmaxf(acc[2], acc[3]));          \
      mx = fmaxf(mx, __shfl_xor(mx, 16));                                      \
      mx = fmaxf(mx, __shfl_xor(mx, 32));                                      \
      float e0 = __expf(acc[0] - mx), e1 = __expf(acc[1] - mx);                \
      float e2 = __expf(acc[2] - mx), e3 = __expf(acc[3] - mx);                \
      float sm = e0 + e1 + e2 + e3;                                            \
      sm += __shfl_xor(sm, 16);                                                \
      sm += __shfl_xor(sm, 32);                                                \
      float inv = 1.f / sm;                                                    \
      CF[0] = e0 * inv; CF[1] = e1 * inv; CF[2] = e2 * inv; CF[3] = e3 * inv;  \
      cT[(gq * 4 + 0) * XP + mcol] = (short)f2bf(CF[0]);                       \
      cT[(gq * 4 + 1) * XP + mcol] = (short)f2bf(CF[1]);                       \
      cT[(gq * 4 + 2) * XP + mcol] = (short)f2bf(CF[2]);                       \
      cT[(gq * 4 + 3) * XP + mcol] = (short)f2bf(CF[3]);                       \
    }
    LOGIT_TILE(0, c_fA)
    LOGIT_TILE(1, c_fB)
#undef LOGIT_TILE

    if (LAST) {
#define CP_TILE(NT2, CF)                                                       \
      {                                                                        \
        const int nt = 2 * w + NT2;                                            \
        _Pragma("unroll")                                                      \
        for (int r = 0; r < 4; ++r) {                                          \
          float v = CF[r];                                                     \
          v += __shfl_xor(v, 1); v += __shfl_xor(v, 2); v += __shfl_xor(v, 4); \
          if ((lane & 7) == 0)                                                 \
            cp_s[nt * 2 + ((lane >> 3) & 1)][gq * 4 + r] = v;                  \
        }                                                                      \
      }
      CP_TILE(0, c_fA)
      CP_TILE(1, c_fB)
#undef CP_TILE
    }
  }
  __syncthreads();

  // ---- GEMM2: y[k][o] = sum_m xT[k][m]*c[m][o] -> y_lds[o][k] ----
  {
    const int oc = lane & 15, gq = lane >> 4;
    f32x4 y0 = {0.f, 0.f, 0.f, 0.f}, y1 = {0.f, 0.f, 0.f, 0.f};
#pragma unroll
    for (int ks = 0; ks < 4; ++ks) {
      short8 bf = *(const short8*)&cT[oc * XP + ks * 32 + gq * 8];
      short8 a0 = *(const short8*)&xT[((2 * w + 0) * 16 + oc) * XP + ks * 32 + gq * 8];
      short8 a1 = *(const short8*)&xT[((2 * w + 1) * 16 + oc) * XP + ks * 32 + gq * 8];
      y0 = __builtin_amdgcn_mfma_f32_16x16x32_bf16(a0, bf, y0, 0, 0, 0);
      y1 = __builtin_amdgcn_mfma_f32_16x16x32_bf16(a1, bf, y1, 0, 0, 0);
    }
#pragma unroll
    for (int r = 0; r < 4; ++r) {
      y_lds[oc * YLP + (2 * w + 0) * 16 + gq * 4 + r] = y0[r];
      y_lds[oc * YLP + (2 * w + 1) * 16 + gq * 4 + r] = y1[r];
    }
  }
  __syncthreads();
  // atomic accumulate into y[g][o][k] (16 chunk-blocks sum per graph)
  {
    float* yp = y_out + (size_t)g * (O_ * OUTD);
    const int oo = t >> 4, k8 = (t & 15) * 8;
    const float* sp = &y_lds[oo * YLP + k8];
#pragma unroll
    for (int e = 0; e < 8; ++e)
      unsafeAtomicAdd(&yp[oo * OUTD + k8 + e], sp[e]);
  }

  // ---- routed partials (last): atomicAdd into routed[g][o][j] ----
  if (LAST) {
    float* rp = routed + (size_t)g * 768;
#pragma unroll
    for (int e = 0; e < 3; ++e) {
      int idx = t + 256 * e;
      int o = idx / VC, j = idx % VC;
      float acc = 0.f;
#pragma unroll
      for (int n = 0; n < 16; ++n) acc += cp_s[n][o] * xv_s[n * VC + j];
      unsafeAtomicAdd(&rp[idx], acc);
    }
  }
}

// ---------------------------------------------------------------------------
// capsB_t<FIRST,LAST>: block (g, o) -- 512 blocks, 2/CU.
//   y from single load (pre-reduced by atomics); s-GEMM k-split 2-way
//   (W indexed by LOCAL k in [0,64); yB by kbase+kl -- R9's OOB fixed);
//   squash; !LAST: wvacc via 2-way split + shfl; LAST: caps + vecs.
// ---------------------------------------------------------------------------
template<int FIRST, int LAST>
__global__ __launch_bounds__(256) void capsB_t(
    const float* __restrict__ y_in, const float* __restrict__ ysum,
    const float* __restrict__ Ws, const float* __restrict__ Wv,
    const float* __restrict__ bias, float* __restrict__ wvacc,
    float* __restrict__ caps, const float* __restrict__ routed,
    float* __restrict__ vecs)
{
  const int b = blockIdx.x, g = b >> 4, o = b & 15, t = threadIdx.x;
  __shared__ float yB[128];
  __shared__ float ps[2][128];
  __shared__ float vB[64];
  __shared__ float pn_s[2];

  if (t < 128) {
    yB[t] = FIRST ? ysum[(size_t)g * 128 + t] * 0.0625f
                  : y_in[((size_t)g * O_ + o) * OUTD + t];
  }
  __syncthreads();

  // s-GEMM, k-split 2-way: thread (kh, d); kl = local contraction idx [0,64)
  {
    const int kh = t >> 7, d = t & 127;
    const float* W = (d < 64) ? (Ws + (size_t)o * 4096 + d)
                              : (Wv + (size_t)o * 4096 + (d - 64));
    const int ybase = (d < 64) ? 0 : 64;
    float a0 = 0.f, a1 = 0.f;
#pragma unroll
    for (int k = 0; k < 32; k += 2) {
      const int kl = kh * 32 + k;
      a0 += yB[ybase + kl] * W[(size_t)kl * 64];
      a1 += yB[ybase + kl + 1] * W[(size_t)(kl + 1) * 64];
    }
    ps[kh][d] = a0 + a1;
  }
  __syncthreads();

  float sv = 0.f;
  if (t < 128) {
    sv = ps[0][t] + ps[1][t] + bias[o * OUTD + t];
    float pn = sv * sv;
#pragma unroll
    for (int m = 1; m < 64; m <<= 1) pn += __shfl_xor(pn, m);
    if ((t & 63) == 0) pn_s[t >> 6] = pn;
  }
  __syncthreads();
  if (t < 128) {
    float sn = pn_s[0] + pn_s[1];
    float f = sn / ((1.f + sn) * (sqrtf(sn) + 1e-8f));
    float v = f * sv;
    if (t < 64) vB[t] = v;
    if (LAST) caps[((size_t)g * O_ + o) * OUTD + t] = v;
  }
  __syncthreads();

  if (!LAST) {
    // wvacc[o][k] = (FIRST?0:old) + sum_s Ws[o][k][s]*v[s], 2-way s-split
    if (t < 128) {
      const int k = t >> 1, half = t & 1;
      const float* Wr = Ws + ((size_t)o * 64 + k) * 64 + half * 32;
      float acc = 0.f;
#pragma unroll
      for (int ss = 0; ss < 32; ss += 4) {
        float4 wq = *(const float4*)(Wr + ss);
        float4 vq = *(const float4*)&vB[half * 32 + ss];
        acc += wq.x * vq.x + wq.y * vq.y + wq.z * vq.z + wq.w * vq.w;
      }
      acc += __shfl_xor(acc, 1);
      if (half == 0) {
        float* wa = wvacc + ((size_t)g * O_ + o) * 64 + k;
        *wa = (FIRST ? 0.f : *wa) + acc;
      }
    }
  } else {
    if (t < 48) {
      vecs[(size_t)g * 768 + o * VC + t] = routed[(size_t)g * 768 + o * VC + t];
    }
  }
}

// ---------------------------------------------------------------------------
extern "C" void kernel_launch(void* const* d_in, const int* in_sizes, int n_in,
                              void* d_out, int out_size, void* d_ws, size_t ws_size,
                              hipStream_t stream)
{
  const float* x    = (const float*)d_in[0];
  const float* xv   = (const float*)d_in[1];
  const float* Ws   = (const float*)d_in[2];
  const float* Wv   = (const float*)d_in[3];
  const float* bias = (const float*)d_in[4];

  float* out  = (float*)d_out;
  float* caps = out;                           // (32,16,128)
  float* vecs = out + (size_t)G_ * O_ * OUTD;  // (32,16,16,3)

  // ws layout (floats):
  //   wvacc 32768 | [zeroed: ysum 4096 | y1 65536 | y2 65536 | routed 24576]
  //   | xTg (bf16: 8388608 elems)
  float* ws     = (float*)d_ws;
  float* wvacc  = ws;
  float* ysum   = ws + 32768;
  float* y1     = ysum + 4096;
  float* y2     = y1 + 65536;
  float* routed = y2 + 65536;
  short* xTg    = (short*)(routed + 24576);

  // zero the atomic accumulators (0.64 MB, ~0.1 us; graph-capture-safe)
  hipMemsetAsync((void*)ysum, 0, (4096 + 65536 + 65536 + 24576) * sizeof(float),
                 stream);

  dim3 blk(256), grdA(G_ * CPG), grdB(G_ * O_);

  // it 0: stage x once; y0 is rank-1 -> ysum path in capsB
  stage_x<<<grdA, blk, 0, stream>>>(x, xTg, ysum);
  capsB_t<1, 0><<<grdB, blk, 0, stream>>>(y1, ysum, Ws, Wv, bias, wvacc,
                                          caps, routed, vecs);
  // it 1
  capsA_t<0><<<grdA, blk, 0, stream>>>(xTg, xv, wvacc, y1, routed);
  capsB_t<0, 0><<<grdB, blk, 0, stream>>>(y1, ysum, Ws, Wv, bias, wvacc,
                                          caps, routed, vecs);
  // it 2 (final)
  capsA_t<1><<<grdA, blk, 0, stream>>>(xTg, xv, wvacc, y2, routed);
  capsB_t<0, 1><<<grdB, blk, 0, stream>>>(y2, ysum, Ws, Wv, bias, wvacc,
                                          caps, routed, vecs);
}

// Round 11
// 40.892 us; speedup vs baseline: 2.3677x; 2.3677x over previous
//
#include <hip/hip_runtime.h>

// Fixed sizes
#define G_    32
#define O_    16
#define OUTD  128
#define DS_   64      // scalar half / SDIM
#define VC    48      // V*3
#define M_    2048    // rows per graph
#define ROWS  128     // rows per chunk
#define CPG   16      // chunks per graph
#define XP    136     // xT / cT pitch in bf16 elems (rows 16B-aligned: 272B)
#define XPD   68      // pitch in dwords
#define WVP   72      // wv_s pitch in bf16
#define YLP   132     // y_lds pitch in f32

typedef __attribute__((ext_vector_type(8))) short short8;
typedef __attribute__((ext_vector_type(4))) float f32x4;
typedef unsigned long long u64_t;

__device__ __forceinline__ unsigned short f2bf(float f) {
  unsigned u = __float_as_uint(f);
  return (unsigned short)((u + 0x7FFFu + ((u >> 16) & 1u)) >> 16);
}
__device__ __forceinline__ float bf2f(short v) {
  return __uint_as_float(((unsigned)(unsigned short)v) << 16);
}

// 8B coherent I/O: relaxed agent-scope u64 atomics (R6/R7-validated).
__device__ __forceinline__ void st8f(float* p, float a, float b) {
  union { float f[2]; u64_t u; } x; x.f[0] = a; x.f[1] = b;
  __hip_atomic_store((u64_t*)p, x.u, __ATOMIC_RELAXED, __HIP_MEMORY_SCOPE_AGENT);
}
__device__ __forceinline__ void ld8f(const float* p, float& a, float& b) {
  union { float f[2]; u64_t u; } x;
  x.u = __hip_atomic_load((const u64_t*)p, __ATOMIC_RELAXED, __HIP_MEMORY_SCOPE_AGENT);
  a = x.f[0]; b = x.f[1];
}

// Per-graph barrier (now 16 blocks/graph), fence-free (R6/R7-validated).
__device__ __forceinline__ void graph_barrier(unsigned* cnt, unsigned target) {
  asm volatile("s_waitcnt vmcnt(0)" ::: "memory");
  __syncthreads();
  if (threadIdx.x == 0) {
    __hip_atomic_fetch_add(cnt, 1u, __ATOMIC_RELAXED, __HIP_MEMORY_SCOPE_AGENT);
    unsigned guard = 0;
    while (__hip_atomic_load(cnt, __ATOMIC_RELAXED, __HIP_MEMORY_SCOPE_AGENT) < target) {
      __builtin_amdgcn_s_sleep(1);
      if (++guard > (1u << 20)) break;
    }
  }
  __syncthreads();
}

// ---------------------------------------------------------------------------
// Occupancy-doubled mega: grid 512 x 512thr, ONE chunk per block, ~56 KB LDS
//  -> 2 blocks/CU co-resident, 16 waves/CU (2x R7's latency hiding).
//  Block b: g = b>>4, chunk = b&15 (chunk doubles as o in B-role).
// ---------------------------------------------------------------------------
__global__ __launch_bounds__(512) void caps_mega2(
    const float* __restrict__ x, const float* __restrict__ xv,
    const float* __restrict__ Ws, const float* __restrict__ Wv,
    const float* __restrict__ bias, short* __restrict__ wvacc_bf,
    float* __restrict__ y_part, float* __restrict__ routed_part,
    float* __restrict__ ysum_part, float* __restrict__ caps,
    float* __restrict__ vecs, unsigned* __restrict__ bar)
{
  const int b = blockIdx.x, g = b >> 4, chunk = b & 15;
  const int t = threadIdx.x, h = t >> 8, tt = t & 255;
  const int lane = t & 63, w = t >> 6;   // 8 waves

  __shared__ short xT[128 * XP];        // 34816 B, persistent
  __shared__ short cT[O_ * XP];         // 4352 B
  __shared__ short wv_s[O_ * WVP];      // 2304 B
  __shared__ float y_lds[16 * YLP];     // 8448 B
  __shared__ float cp_s[16][17];        // 1088 B
  __shared__ float xv_s[16 * VC];       // 3072 B
  __shared__ float yB[128];             // 512 B
  __shared__ float ps[2][128];          // 1024 B
  __shared__ float vB[64];              // 256 B
  __shared__ float pn_s[2];             // 8 B
  __shared__ float wv_acc_s[64];        // 256 B, persistent accumulator
  // total ~56.1 KB -> 2 blocks/CU

  unsigned* cnt = bar + g * 64;

  // ========== phase 0: stage x -> xT (512 thr: h = col-16 half) ============
  {
    const float* xg = x + (size_t)b * (ROWS * OUTD);
    const int rg = tt >> 2, qc = tt & 3;
    const float* r0 = xg + (size_t)(2 * rg) * OUTD + qc * 32 + h * 16;
    const float* r1 = r0 + OUTD;
    const float4* r0q = (const float4*)r0;
    const float4* r1q = (const float4*)r1;
    float4 a0 = r0q[0], a1 = r0q[1], a2 = r0q[2], a3 = r0q[3];
    float4 b0 = r1q[0], b1 = r1q[1], b2 = r1q[2], b3 = r1q[3];
    unsigned* xTd = (unsigned*)xT;
    const int cb = qc * 32 + h * 16;
#define STAGE4(S, A, B)                                                        \
    xTd[(cb + S*4 + 0) * XPD + rg] = (unsigned)f2bf(A.x) | ((unsigned)f2bf(B.x) << 16); \
    xTd[(cb + S*4 + 1) * XPD + rg] = (unsigned)f2bf(A.y) | ((unsigned)f2bf(B.y) << 16); \
    xTd[(cb + S*4 + 2) * XPD + rg] = (unsigned)f2bf(A.z) | ((unsigned)f2bf(B.z) << 16); \
    xTd[(cb + S*4 + 3) * XPD + rg] = (unsigned)f2bf(A.w) | ((unsigned)f2bf(B.w) << 16);
    STAGE4(0, a0, b0) STAGE4(1, a1, b1) STAGE4(2, a2, b2) STAGE4(3, a3, b3)
#undef STAGE4
  }
  {
    const float* xvg = xv + (size_t)(g * 256 + chunk * 16) * VC;
    for (int i = t; i < 16 * VC; i += 512) xv_s[i] = xvg[i];
  }
  __syncthreads();
  if (h == 0) {   // colsums (R7-validated pattern)
    const int k = tt >> 1, half = tt & 1;
    float s = 0.f;
#pragma unroll
    for (int j = 0; j < 8; ++j) {
      short8 v = *(const short8*)&xT[k * XP + half * 64 + j * 8];
#pragma unroll
      for (int e = 0; e < 8; ++e) s += bf2f(v[e]);
    }
    s += __shfl_xor(s, 1);
    float s1 = __shfl_xor(s, 2);
    if ((tt & 3) == 0) st8f(&ysum_part[(size_t)b * 128 + k], s, s1);
  }
  graph_barrier(cnt, 16);

  // ---- role macros ---------------------------------------------------------
#define A_ROLE(LASTF)                                                          \
  {                                                                            \
    if (t < 256) {                                                             \
      u64_t v4 = __hip_atomic_load(                                            \
          (const u64_t*)&wvacc_bf[(size_t)g * 1024 + t * 4],                   \
          __ATOMIC_RELAXED, __HIP_MEMORY_SCOPE_AGENT);                         \
      const int o = t >> 4, k = (t * 4) & 63;                                  \
      wv_s[o * WVP + k + 0] = (short)(v4 & 0xFFFF);                            \
      wv_s[o * WVP + k + 1] = (short)((v4 >> 16) & 0xFFFF);                    \
      wv_s[o * WVP + k + 2] = (short)((v4 >> 32) & 0xFFFF);                    \
      wv_s[o * WVP + k + 3] = (short)((v4 >> 48) & 0xFFFF);                    \
    }                                                                          \
    __syncthreads();                                                           \
    /* GEMM1 + softmax: wave w owns m-tile nt = w */                           \
    { const int mrow = lane & 15, gq = lane >> 4;                              \
      const int nt = w;                                                        \
      const int mcol = nt * 16 + mrow;                                         \
      f32x4 acc = {0.f, 0.f, 0.f, 0.f};                                        \
      _Pragma("unroll")                                                        \
      for (int ks = 0; ks < 2; ++ks) {                                         \
        short8 af = *(const short8*)&wv_s[mrow * WVP + ks * 32 + gq * 8];      \
        short8 bfr;                                                            \
        _Pragma("unroll")                                                      \
        for (int e = 0; e < 8; ++e)                                            \
          bfr[e] = xT[(ks * 32 + gq * 8 + e) * XP + mcol];                     \
        acc = __builtin_amdgcn_mfma_f32_16x16x32_bf16(af, bfr, acc, 0, 0, 0);  \
      }                                                                        \
      float mx = fmaxf(fmaxf(acc[0], acc[1]), fmaxf(acc[2], acc[3]));          \
      mx = fmaxf(mx, __shfl_xor(mx, 16));                                      \
      mx = fmaxf(mx, __shfl_xor(mx, 32));                                      \
      float e0 = __expf(acc[0] - mx), e1 = __expf(acc[1] - mx);                \
      float e2 = __expf(acc[2] - mx), e3 = __expf(acc[3] - mx);                \
      float sm = e0 + e1 + e2 + e3;                                            \
      sm += __shfl_xor(sm, 16);                                                \
      sm += __shfl_xor(sm, 32);                                                \
      float inv = 1.f / sm;                                                    \
      float c0 = e0 * inv, c1 = e1 * inv, c2 = e2 * inv, c3 = e3 * inv;        \
      cT[(gq * 4 + 0) * XP + mcol] = (short)f2bf(c0);                          \
      cT[(gq * 4 + 1) * XP + mcol] = (short)f2bf(c1);                          \
      cT[(gq * 4 + 2) * XP + mcol] = (short)f2bf(c2);                          \
      cT[(gq * 4 + 3) * XP + mcol] = (short)f2bf(c3);                          \
      if (LASTF) {                                                             \
        float cf[4] = {c0, c1, c2, c3};                                        \
        _Pragma("unroll")                                                      \
        for (int r = 0; r < 4; ++r) {                                          \
          float v = cf[r];                                                     \
          v += __shfl_xor(v, 1); v += __shfl_xor(v, 2); v += __shfl_xor(v, 4); \
          if ((lane & 7) == 0)                                                 \
            cp_s[nt * 2 + ((lane >> 3) & 1)][gq * 4 + r] = v;                  \
        }                                                                      \
      } }                                                                      \
    __syncthreads();                                                           \
    /* GEMM2: wave w owns k-tile w */                                          \
    { const int oc = lane & 15, gq = lane >> 4;                                \
      f32x4 y0 = {0.f,0.f,0.f,0.f};                                            \
      _Pragma("unroll")                                                        \
      for (int ks = 0; ks < 4; ++ks) {                                         \
        short8 bfv = *(const short8*)&cT[oc * XP + ks * 32 + gq * 8];          \
        short8 av = *(const short8*)&xT[(w * 16 + oc) * XP + ks * 32 + gq * 8];\
        y0 = __builtin_amdgcn_mfma_f32_16x16x32_bf16(av, bfv, y0, 0, 0, 0);    \
      }                                                                        \
      _Pragma("unroll")                                                        \
      for (int r = 0; r < 4; ++r)                                              \
        y_lds[oc * YLP + w * 16 + gq * 4 + r] = y0[r]; }                       \
    __syncthreads();                                                           \
    { float* yp = y_part + (size_t)b * 2048;                                   \
      const int oo = t >> 5, kk = (t * 4) & 127;                               \
      const float* sp = &y_lds[oo * YLP + kk];                                 \
      st8f(&yp[t * 4], sp[0], sp[1]);                                          \
      st8f(&yp[t * 4 + 2], sp[2], sp[3]); }                                    \
    if (LASTF) {                                                               \
      if (t < 384) {                                                           \
        float* rp = routed_part + (size_t)b * 768;                             \
        const int idx0 = 2 * t;                                                \
        const int o = idx0 / VC, j = idx0 - o * VC;                            \
        float a0 = 0.f, a1 = 0.f;                                              \
        _Pragma("unroll")                                                      \
        for (int n = 0; n < 16; ++n) {                                         \
          a0 += cp_s[n][o] * xv_s[n * VC + j];                                 \
          a1 += cp_s[n][o] * xv_s[n * VC + j + 1];                             \
        }                                                                      \
        st8f(&rp[idx0], a0, a1);                                               \
      } }                                                                      \
  }

#define B_ROLE(FIRSTF, LASTF)                                                  \
  {                                                                            \
    const int o = chunk;                                                       \
    if (t < 64) {                                                              \
      float s0 = 0.f, s1 = 0.f;                                                \
      if (FIRSTF) {                                                            \
        _Pragma("unroll")                                                      \
        for (int ch = 0; ch < CPG; ++ch) {                                     \
          float a, bb;                                                         \
          ld8f(&ysum_part[(size_t)(g * CPG + ch) * 128 + 2 * t], a, bb);       \
          s0 += a; s1 += bb;                                                   \
        }                                                                      \
        s0 *= 0.0625f; s1 *= 0.0625f;                                          \
      } else {                                                                 \
        const float* yp = y_part + (size_t)g * CPG * 2048 + o * 128 + 2 * t;   \
        _Pragma("unroll")                                                      \
        for (int ch = 0; ch < CPG; ++ch) {                                     \
          float a, bb; ld8f(&yp[ch * 2048], a, bb);                            \
          s0 += a; s1 += bb;                                                   \
        }                                                                      \
      }                                                                        \
      yB[2*t] = s0; yB[2*t+1] = s1;                                            \
    }                                                                          \
    __syncthreads();                                                           \
    if (t < 256) {   /* s-GEMM, k-split 2-way (R10-validated) */               \
      const int kh = t >> 7, d = t & 127;                                      \
      const float* W = (d < 64) ? (Ws + (size_t)o * 4096 + d)                  \
                                : (Wv + (size_t)o * 4096 + (d - 64));          \
      const int ybase = (d < 64) ? 0 : 64;                                     \
      float a0 = 0.f, a1 = 0.f;                                                \
      _Pragma("unroll")                                                        \
      for (int k = 0; k < 32; k += 2) {                                        \
        const int kl = kh * 32 + k;                                            \
        a0 += yB[ybase + kl] * W[(size_t)kl * 64];                             \
        a1 += yB[ybase + kl + 1] * W[(size_t)(kl + 1) * 64];                   \
      }                                                                        \
      ps[kh][d] = a0 + a1;                                                     \
    }                                                                          \
    __syncthreads();                                                           \
    float sv = 0.f;                                                            \
    if (t < 128) {                                                             \
      sv = ps[0][t] + ps[1][t] + bias[o * OUTD + t];                           \
      float pn = sv * sv;                                                      \
      _Pragma("unroll")                                                        \
      for (int m = 1; m < 64; m <<= 1) pn += __shfl_xor(pn, m);                \
      if ((t & 63) == 0) pn_s[t >> 6] = pn;                                    \
    }                                                                          \
    __syncthreads();                                                           \
    if (t < 128) {                                                             \
      float sn = pn_s[0] + pn_s[1];                                            \
      float f = sn / ((1.f + sn) * (sqrtf(sn) + 1e-8f));                       \
      float v = f * sv;                                                        \
      if (t < 64) vB[t] = v;                                                   \
      if (LASTF) caps[((size_t)g * O_ + o) * OUTD + t] = v;                    \
    }                                                                          \
    __syncthreads();                                                           \
    if (!(LASTF)) {                                                            \
      if (t < 128) {  /* wvacc update, 2-way s-split (R10-validated) */        \
        const int k = t >> 1, half = t & 1;                                    \
        const float* Wr = Ws + ((size_t)o * 64 + k) * 64 + half * 32;          \
        float acc = 0.f;                                                       \
        _Pragma("unroll")                                                      \
        for (int ss = 0; ss < 32; ss += 4) {                                   \
          float4 wq = *(const float4*)(Wr + ss);                               \
          float4 vq = *(const float4*)&vB[half * 32 + ss];                     \
          acc += wq.x*vq.x + wq.y*vq.y + wq.z*vq.z + wq.w*vq.w;                \
        }                                                                      \
        acc += __shfl_xor(acc, 1);                                             \
        if (half == 0)                                                         \
          wv_acc_s[k] = ((FIRSTF) ? 0.f : wv_acc_s[k]) + acc;                  \
      }                                                                        \
      __syncthreads();                                                         \
      if (t < 16) {   /* pack bf16 x4 -> u64 coherent store (R7-validated) */  \
        const int k = t * 4;                                                   \
        u64_t v4 =  (u64_t)(unsigned short)f2bf(wv_acc_s[k + 0])               \
                 | ((u64_t)(unsigned short)f2bf(wv_acc_s[k + 1]) << 16)        \
                 | ((u64_t)(unsigned short)f2bf(wv_acc_s[k + 2]) << 32)        \
                 | ((u64_t)(unsigned short)f2bf(wv_acc_s[k + 3]) << 48);       \
        __hip_atomic_store(                                                    \
            (u64_t*)&wvacc_bf[(size_t)g * 1024 + o * 64 + k],                  \
            v4, __ATOMIC_RELAXED, __HIP_MEMORY_SCOPE_AGENT);                   \
      }                                                                        \
    } else {                                                                   \
      if (t < 24) {                                                            \
        const int idx = o * VC + 2 * t;                                        \
        const float* rp = routed_part + (size_t)g * CPG * 768 + idx;           \
        float s0 = 0.f, s1 = 0.f;                                              \
        _Pragma("unroll")                                                      \
        for (int ch = 0; ch < CPG; ++ch) {                                     \
          float a, bb; ld8f(&rp[ch * 768], a, bb);                             \
          s0 += a; s1 += bb;                                                   \
        }                                                                      \
        vecs[(size_t)g * 768 + idx] = s0;                                      \
        vecs[(size_t)g * 768 + idx + 1] = s1;                                  \
      }                                                                        \
    }                                                                          \
  }

  // ================= routing iterations =================
  B_ROLE(1, 0)                 // it0 B: v0 from colsums, wvacc '='
  graph_barrier(cnt, 32);
  A_ROLE(0)                    // it1 A
  graph_barrier(cnt, 48);
  B_ROLE(0, 0)                 // it1 B: wvacc '+='
  graph_barrier(cnt, 64);
  A_ROLE(1)                    // it2 A: + cp + routed partials
  graph_barrier(cnt, 80);
  B_ROLE(0, 1)                 // it2 B: caps + vecs

#undef A_ROLE
#undef B_ROLE
}

// ---------------------------------------------------------------------------
extern "C" void kernel_launch(void* const* d_in, const int* in_sizes, int n_in,
                              void* d_out, int out_size, void* d_ws, size_t ws_size,
                              hipStream_t stream)
{
  const float* x    = (const float*)d_in[0];
  const float* xv   = (const float*)d_in[1];
  const float* Ws   = (const float*)d_in[2];
  const float* Wv   = (const float*)d_in[3];
  const float* bias = (const float*)d_in[4];

  float* out  = (float*)d_out;
  float* caps = out;                           // (32,16,128)
  float* vecs = out + (size_t)G_ * O_ * OUTD;  // (32,16,16,3)

  // ws layout: bar (2048 u32) | ysum_part 65536 f | y_part 1048576 f
  //            | routed 393216 f | wvacc_bf 32768 bf16
  float* ws          = (float*)d_ws;
  unsigned* bar      = (unsigned*)ws;
  float* ysum_part   = ws + 4096;
  float* y_part      = ysum_part + (size_t)G_ * CPG * 128;
  float* routed_part = y_part + (size_t)G_ * CPG * 2048;
  short* wvacc_bf    = (short*)(routed_part + (size_t)G_ * CPG * 768);

  hipMemsetAsync((void*)bar, 0, (size_t)G_ * 64 * sizeof(unsigned), stream);
  caps_mega2<<<dim3(G_ * CPG), dim3(512), 0, stream>>>(
      x, xv, Ws, Wv, bias, wvacc_bf, y_part, routed_part, ysum_part,
      caps, vecs, bar);
}

// Round 12
// 39.749 us; speedup vs baseline: 2.4358x; 1.0287x over previous
//
#include <hip/hip_runtime.h>

// Fixed sizes
#define G_    32
#define O_    16
#define OUTD  128
#define DS_   64      // scalar half / SDIM
#define VC    48      // V*3
#define M_    2048    // rows per graph
#define ROWS  128     // rows per chunk
#define CPG   16      // chunks per graph
#define XP    136     // xT / cT pitch in bf16 elems (rows 16B-aligned: 272B)
#define XPD   68      // pitch in dwords
#define WVP   72      // wv_s pitch in bf16
#define XNP   72      // xN pitch in bf16 (row-major scalar half)
#define YLP   132     // y_lds pitch in f32

typedef __attribute__((ext_vector_type(8))) short short8;
typedef __attribute__((ext_vector_type(4))) float f32x4;
typedef unsigned long long u64_t;

__device__ __forceinline__ unsigned short f2bf(float f) {
  unsigned u = __float_as_uint(f);
  return (unsigned short)((u + 0x7FFFu + ((u >> 16) & 1u)) >> 16);
}
__device__ __forceinline__ float bf2f(short v) {
  return __uint_as_float(((unsigned)(unsigned short)v) << 16);
}

// 8B coherent I/O: relaxed agent-scope u64 atomics (R6/R7-validated).
__device__ __forceinline__ void st8f(float* p, float a, float b) {
  union { float f[2]; u64_t u; } x; x.f[0] = a; x.f[1] = b;
  __hip_atomic_store((u64_t*)p, x.u, __ATOMIC_RELAXED, __HIP_MEMORY_SCOPE_AGENT);
}
__device__ __forceinline__ void ld8f(const float* p, float& a, float& b) {
  union { float f[2]; u64_t u; } x;
  x.u = __hip_atomic_load((const u64_t*)p, __ATOMIC_RELAXED, __HIP_MEMORY_SCOPE_AGENT);
  a = x.f[0]; b = x.f[1];
}

// Per-graph barrier (16 blocks/graph), fence-free (R6/R7/R11-validated).
__device__ __forceinline__ void graph_barrier(unsigned* cnt, unsigned target) {
  asm volatile("s_waitcnt vmcnt(0)" ::: "memory");
  __syncthreads();
  if (threadIdx.x == 0) {
    __hip_atomic_fetch_add(cnt, 1u, __ATOMIC_RELAXED, __HIP_MEMORY_SCOPE_AGENT);
    unsigned guard = 0;
    while (__hip_atomic_load(cnt, __ATOMIC_RELAXED, __HIP_MEMORY_SCOPE_AGENT) < target) {
      __builtin_amdgcn_s_sleep(1);
      if (++guard > (1u << 20)) break;
    }
  }
  __syncthreads();
}

// ---------------------------------------------------------------------------
// R12 = R11 + dual x layout in LDS:
//   xT [k][m] (transposed)  -> GEMM2 A-operand (contiguous b128 reads)
//   xN [m][k] (row-major, scalar half only) -> GEMM1 B-operand: replaces
//   16 scalar ds_read_u16/thread (4-way conflicts on banks 0-7, 1.08M
//   SQ_LDS_BANK_CONFLICT in R11) with two ds_read_b128 at 2-way (free).
//  Grid 512 x 512thr, ~74.6 KB LDS -> 2 blocks/CU (16 waves/CU).
// ---------------------------------------------------------------------------
__global__ __launch_bounds__(512) void caps_mega3(
    const float* __restrict__ x, const float* __restrict__ xv,
    const float* __restrict__ Ws, const float* __restrict__ Wv,
    const float* __restrict__ bias, short* __restrict__ wvacc_bf,
    float* __restrict__ y_part, float* __restrict__ routed_part,
    float* __restrict__ ysum_part, float* __restrict__ caps,
    float* __restrict__ vecs, unsigned* __restrict__ bar)
{
  const int b = blockIdx.x, g = b >> 4, chunk = b & 15;
  const int t = threadIdx.x, h = t >> 8, tt = t & 255;
  const int lane = t & 63, w = t >> 6;   // 8 waves

  __shared__ short xT[128 * XP];        // 34816 B, persistent
  __shared__ short xN[128 * XNP];       // 18432 B, persistent (scalar half)
  __shared__ short cT[O_ * XP];         // 4352 B
  __shared__ short wv_s[O_ * WVP];      // 2304 B
  __shared__ float y_lds[16 * YLP];     // 8448 B
  __shared__ float cp_s[16][17];        // 1088 B
  __shared__ float xv_s[16 * VC];       // 3072 B
  __shared__ float yB[128];             // 512 B
  __shared__ float ps[2][128];          // 1024 B
  __shared__ float vB[64];              // 256 B
  __shared__ float pn_s[2];             // 8 B
  __shared__ float wv_acc_s[64];        // 256 B
  // total ~74.6 KB -> 2 blocks/CU

  unsigned* cnt = bar + g * 64;

  // ========== phase 0: stage x -> xT (+ xN for k<64) ========================
  {
    const float* xg = x + (size_t)b * (ROWS * OUTD);
    const int rg = tt >> 2, qc = tt & 3;
    const float* r0 = xg + (size_t)(2 * rg) * OUTD + qc * 32 + h * 16;
    const float* r1 = r0 + OUTD;
    const float4* r0q = (const float4*)r0;
    const float4* r1q = (const float4*)r1;
    float4 a0 = r0q[0], a1 = r0q[1], a2 = r0q[2], a3 = r0q[3];
    float4 b0 = r1q[0], b1 = r1q[1], b2 = r1q[2], b3 = r1q[3];
    unsigned* xTd = (unsigned*)xT;
    const int cb = qc * 32 + h * 16;
#define STAGE4(S, A, B)                                                        \
    xTd[(cb + S*4 + 0) * XPD + rg] = (unsigned)f2bf(A.x) | ((unsigned)f2bf(B.x) << 16); \
    xTd[(cb + S*4 + 1) * XPD + rg] = (unsigned)f2bf(A.y) | ((unsigned)f2bf(B.y) << 16); \
    xTd[(cb + S*4 + 2) * XPD + rg] = (unsigned)f2bf(A.z) | ((unsigned)f2bf(B.z) << 16); \
    xTd[(cb + S*4 + 3) * XPD + rg] = (unsigned)f2bf(A.w) | ((unsigned)f2bf(B.w) << 16);
    STAGE4(0, a0, b0) STAGE4(1, a1, b1) STAGE4(2, a2, b2) STAGE4(3, a3, b3)
#undef STAGE4
    // row-major copy (scalar half only, cols < 64): 4x short8 stores
    if (qc < 2) {
      short8 p0, p1, q0, q1;
      p0[0]=f2bf(a0.x); p0[1]=f2bf(a0.y); p0[2]=f2bf(a0.z); p0[3]=f2bf(a0.w);
      p0[4]=f2bf(a1.x); p0[5]=f2bf(a1.y); p0[6]=f2bf(a1.z); p0[7]=f2bf(a1.w);
      p1[0]=f2bf(a2.x); p1[1]=f2bf(a2.y); p1[2]=f2bf(a2.z); p1[3]=f2bf(a2.w);
      p1[4]=f2bf(a3.x); p1[5]=f2bf(a3.y); p1[6]=f2bf(a3.z); p1[7]=f2bf(a3.w);
      q0[0]=f2bf(b0.x); q0[1]=f2bf(b0.y); q0[2]=f2bf(b0.z); q0[3]=f2bf(b0.w);
      q0[4]=f2bf(b1.x); q0[5]=f2bf(b1.y); q0[6]=f2bf(b1.z); q0[7]=f2bf(b1.w);
      q1[0]=f2bf(b2.x); q1[1]=f2bf(b2.y); q1[2]=f2bf(b2.z); q1[3]=f2bf(b2.w);
      q1[4]=f2bf(b3.x); q1[5]=f2bf(b3.y); q1[6]=f2bf(b3.z); q1[7]=f2bf(b3.w);
      *(short8*)&xN[(2 * rg + 0) * XNP + cb]     = p0;
      *(short8*)&xN[(2 * rg + 0) * XNP + cb + 8] = p1;
      *(short8*)&xN[(2 * rg + 1) * XNP + cb]     = q0;
      *(short8*)&xN[(2 * rg + 1) * XNP + cb + 8] = q1;
    }
  }
  {
    const float* xvg = xv + (size_t)(g * 256 + chunk * 16) * VC;
    for (int i = t; i < 16 * VC; i += 512) xv_s[i] = xvg[i];
  }
  __syncthreads();
  if (h == 0) {   // colsums (R7-validated pattern)
    const int k = tt >> 1, half = tt & 1;
    float s = 0.f;
#pragma unroll
    for (int j = 0; j < 8; ++j) {
      short8 v = *(const short8*)&xT[k * XP + half * 64 + j * 8];
#pragma unroll
      for (int e = 0; e < 8; ++e) s += bf2f(v[e]);
    }
    s += __shfl_xor(s, 1);
    float s1 = __shfl_xor(s, 2);
    if ((tt & 3) == 0) st8f(&ysum_part[(size_t)b * 128 + k], s, s1);
  }
  graph_barrier(cnt, 16);

  // ---- role macros ---------------------------------------------------------
#define A_ROLE(LASTF)                                                          \
  {                                                                            \
    if (t < 256) {                                                             \
      u64_t v4 = __hip_atomic_load(                                            \
          (const u64_t*)&wvacc_bf[(size_t)g * 1024 + t * 4],                   \
          __ATOMIC_RELAXED, __HIP_MEMORY_SCOPE_AGENT);                         \
      const int o = t >> 4, k = (t * 4) & 63;                                  \
      wv_s[o * WVP + k + 0] = (short)(v4 & 0xFFFF);                            \
      wv_s[o * WVP + k + 1] = (short)((v4 >> 16) & 0xFFFF);                    \
      wv_s[o * WVP + k + 2] = (short)((v4 >> 32) & 0xFFFF);                    \
      wv_s[o * WVP + k + 3] = (short)((v4 >> 48) & 0xFFFF);                    \
    }                                                                          \
    __syncthreads();                                                           \
    /* GEMM1 + softmax: wave w owns m-tile nt = w; B-op from xN (b128) */      \
    { const int mrow = lane & 15, gq = lane >> 4;                              \
      const int nt = w;                                                        \
      const int mcol = nt * 16 + mrow;                                         \
      f32x4 acc = {0.f, 0.f, 0.f, 0.f};                                        \
      _Pragma("unroll")                                                        \
      for (int ks = 0; ks < 2; ++ks) {                                         \
        short8 af = *(const short8*)&wv_s[mrow * WVP + ks * 32 + gq * 8];      \
        short8 bfr = *(const short8*)&xN[mcol * XNP + ks * 32 + gq * 8];       \
        acc = __builtin_amdgcn_mfma_f32_16x16x32_bf16(af, bfr, acc, 0, 0, 0);  \
      }                                                                        \
      float mx = fmaxf(fmaxf(acc[0], acc[1]), fmaxf(acc[2], acc[3]));          \
      mx = fmaxf(mx, __shfl_xor(mx, 16));                                      \
      mx = fmaxf(mx, __shfl_xor(mx, 32));                                      \
      float e0 = __expf(acc[0] - mx), e1 = __expf(acc[1] - mx);                \
      float e2 = __expf(acc[2] - mx), e3 = __expf(acc[3] - mx);                \
      float sm = e0 + e1 + e2 + e3;                                            \
      sm += __shfl_xor(sm, 16);                                                \
      sm += __shfl_xor(sm, 32);                                                \
      float inv = 1.f / sm;                                                    \
      float c0 = e0 * inv, c1 = e1 * inv, c2 = e2 * inv, c3 = e3 * inv;        \
      cT[(gq * 4 + 0) * XP + mcol] = (short)f2bf(c0);                          \
      cT[(gq * 4 + 1) * XP + mcol] = (short)f2bf(c1);                          \
      cT[(gq * 4 + 2) * XP + mcol] = (short)f2bf(c2);                          \
      cT[(gq * 4 + 3) * XP + mcol] = (short)f2bf(c3);                          \
      if (LASTF) {                                                             \
        float cf[4] = {c0, c1, c2, c3};                                        \
        _Pragma("unroll")                                                      \
        for (int r = 0; r < 4; ++r) {                                          \
          float v = cf[r];                                                     \
          v += __shfl_xor(v, 1); v += __shfl_xor(v, 2); v += __shfl_xor(v, 4); \
          if ((lane & 7) == 0)                                                 \
            cp_s[nt * 2 + ((lane >> 3) & 1)][gq * 4 + r] = v;                  \
        }                                                                      \
      } }                                                                      \
    __syncthreads();                                                           \
    /* GEMM2: wave w owns k-tile w */                                          \
    { const int oc = lane & 15, gq = lane >> 4;                                \
      f32x4 y0 = {0.f,0.f,0.f,0.f};                                            \
      _Pragma("unroll")                                                        \
      for (int ks = 0; ks < 4; ++ks) {                                         \
        short8 bfv = *(const short8*)&cT[oc * XP + ks * 32 + gq * 8];          \
        short8 av = *(const short8*)&xT[(w * 16 + oc) * XP + ks * 32 + gq * 8];\
        y0 = __builtin_amdgcn_mfma_f32_16x16x32_bf16(av, bfv, y0, 0, 0, 0);    \
      }                                                                        \
      _Pragma("unroll")                                                        \
      for (int r = 0; r < 4; ++r)                                              \
        y_lds[oc * YLP + w * 16 + gq * 4 + r] = y0[r]; }                       \
    __syncthreads();                                                           \
    { float* yp = y_part + (size_t)b * 2048;                                   \
      const int oo = t >> 5, kk = (t * 4) & 127;                               \
      const float* sp = &y_lds[oo * YLP + kk];                                 \
      st8f(&yp[t * 4], sp[0], sp[1]);                                          \
      st8f(&yp[t * 4 + 2], sp[2], sp[3]); }                                    \
    if (LASTF) {                                                               \
      if (t < 384) {                                                           \
        float* rp = routed_part + (size_t)b * 768;                             \
        const int idx0 = 2 * t;                                                \
        const int o = idx0 / VC, j = idx0 - o * VC;                            \
        float a0 = 0.f, a1 = 0.f;                                              \
        _Pragma("unroll")                                                      \
        for (int n = 0; n < 16; ++n) {                                         \
          a0 += cp_s[n][o] * xv_s[n * VC + j];                                 \
          a1 += cp_s[n][o] * xv_s[n * VC + j + 1];                             \
        }                                                                      \
        st8f(&rp[idx0], a0, a1);                                               \
      } }                                                                      \
  }

#define B_ROLE(FIRSTF, LASTF)                                                  \
  {                                                                            \
    const int o = chunk;                                                       \
    if (t < 64) {                                                              \
      float s0 = 0.f, s1 = 0.f;                                                \
      if (FIRSTF) {                                                            \
        _Pragma("unroll")                                                      \
        for (int ch = 0; ch < CPG; ++ch) {                                     \
          float a, bb;                                                         \
          ld8f(&ysum_part[(size_t)(g * CPG + ch) * 128 + 2 * t], a, bb);       \
          s0 += a; s1 += bb;                                                   \
        }                                                                      \
        s0 *= 0.0625f; s1 *= 0.0625f;                                          \
      } else {                                                                 \
        const float* yp = y_part + (size_t)g * CPG * 2048 + o * 128 + 2 * t;   \
        _Pragma("unroll")                                                      \
        for (int ch = 0; ch < CPG; ++ch) {                                     \
          float a, bb; ld8f(&yp[ch * 2048], a, bb);                            \
          s0 += a; s1 += bb;                                                   \
        }                                                                      \
      }                                                                        \
      yB[2*t] = s0; yB[2*t+1] = s1;                                            \
    }                                                                          \
    __syncthreads();                                                           \
    if (t < 256) {   /* s-GEMM, k-split 2-way (R10/R11-validated) */           \
      const int kh = t >> 7, d = t & 127;                                      \
      const float* W = (d < 64) ? (Ws + (size_t)o * 4096 + d)                  \
                                : (Wv + (size_t)o * 4096 + (d - 64));          \
      const int ybase = (d < 64) ? 0 : 64;                                     \
      float a0 = 0.f, a1 = 0.f;                                                \
      _Pragma("unroll")                                                        \
      for (int k = 0; k < 32; k += 2) {                                        \
        const int kl = kh * 32 + k;                                            \
        a0 += yB[ybase + kl] * W[(size_t)kl * 64];                             \
        a1 += yB[ybase + kl + 1] * W[(size_t)(kl + 1) * 64];                   \
      }                                                                        \
      ps[kh][d] = a0 + a1;                                                     \
    }                                                                          \
    __syncthreads();                                                           \
    float sv = 0.f;                                                            \
    if (t < 128) {                                                             \
      sv = ps[0][t] + ps[1][t] + bias[o * OUTD + t];                           \
      float pn = sv * sv;                                                      \
      _Pragma("unroll")                                                        \
      for (int m = 1; m < 64; m <<= 1) pn += __shfl_xor(pn, m);                \
      if ((t & 63) == 0) pn_s[t >> 6] = pn;                                    \
    }                                                                          \
    __syncthreads();                                                           \
    if (t < 128) {                                                             \
      float sn = pn_s[0] + pn_s[1];                                            \
      float f = sn / ((1.f + sn) * (sqrtf(sn) + 1e-8f));                       \
      float v = f * sv;                                                        \
      if (t < 64) vB[t] = v;                                                   \
      if (LASTF) caps[((size_t)g * O_ + o) * OUTD + t] = v;                    \
    }                                                                          \
    __syncthreads();                                                           \
    if (!(LASTF)) {                                                            \
      if (t < 128) {  /* wvacc update, 2-way s-split (R10/R11-validated) */    \
        const int k = t >> 1, half = t & 1;                                    \
        const float* Wr = Ws + ((size_t)o * 64 + k) * 64 + half * 32;          \
        float acc = 0.f;                                                       \
        _Pragma("unroll")                                                      \
        for (int ss = 0; ss < 32; ss += 4) {                                   \
          float4 wq = *(const float4*)(Wr + ss);                               \
          float4 vq = *(const float4*)&vB[half * 32 + ss];                     \
          acc += wq.x*vq.x + wq.y*vq.y + wq.z*vq.z + wq.w*vq.w;                \
        }                                                                      \
        acc += __shfl_xor(acc, 1);                                             \
        if (half == 0)                                                         \
          wv_acc_s[k] = ((FIRSTF) ? 0.f : wv_acc_s[k]) + acc;                  \
      }                                                                        \
      __syncthreads();                                                         \
      if (t < 16) {   /* pack bf16 x4 -> u64 coherent store (validated) */     \
        const int k = t * 4;                                                   \
        u64_t v4 =  (u64_t)(unsigned short)f2bf(wv_acc_s[k + 0])               \
                 | ((u64_t)(unsigned short)f2bf(wv_acc_s[k + 1]) << 16)        \
                 | ((u64_t)(unsigned short)f2bf(wv_acc_s[k + 2]) << 32)        \
                 | ((u64_t)(unsigned short)f2bf(wv_acc_s[k + 3]) << 48);       \
        __hip_atomic_store(                                                    \
            (u64_t*)&wvacc_bf[(size_t)g * 1024 + o * 64 + k],                  \
            v4, __ATOMIC_RELAXED, __HIP_MEMORY_SCOPE_AGENT);                   \
      }                                                                        \
    } else {                                                                   \
      if (t < 24) {                                                            \
        const int idx = o * VC + 2 * t;                                        \
        const float* rp = routed_part + (size_t)g * CPG * 768 + idx;           \
        float s0 = 0.f, s1 = 0.f;                                              \
        _Pragma("unroll")                                                      \
        for (int ch = 0; ch < CPG; ++ch) {                                     \
          float a, bb; ld8f(&rp[ch * 768], a, bb);                             \
          s0 += a; s1 += bb;                                                   \
        }                                                                      \
        vecs[(size_t)g * 768 + idx] = s0;                                      \
        vecs[(size_t)g * 768 + idx + 1] = s1;                                  \
      }                                                                        \
    }                                                                          \
  }

  // ================= routing iterations =================
  B_ROLE(1, 0)                 // it0 B: v0 from colsums, wvacc '='
  graph_barrier(cnt, 32);
  A_ROLE(0)                    // it1 A
  graph_barrier(cnt, 48);
  B_ROLE(0, 0)                 // it1 B: wvacc '+='
  graph_barrier(cnt, 64);
  A_ROLE(1)                    // it2 A: + cp + routed partials
  graph_barrier(cnt, 80);
  B_ROLE(0, 1)                 // it2 B: caps + vecs

#undef A_ROLE
#undef B_ROLE
}

// ---------------------------------------------------------------------------
extern "C" void kernel_launch(void* const* d_in, const int* in_sizes, int n_in,
                              void* d_out, int out_size, void* d_ws, size_t ws_size,
                              hipStream_t stream)
{
  const float* x    = (const float*)d_in[0];
  const float* xv   = (const float*)d_in[1];
  const float* Ws   = (const float*)d_in[2];
  const float* Wv   = (const float*)d_in[3];
  const float* bias = (const float*)d_in[4];

  float* out  = (float*)d_out;
  float* caps = out;                           // (32,16,128)
  float* vecs = out + (size_t)G_ * O_ * OUTD;  // (32,16,16,3)

  // ws layout: bar (2048 u32) | ysum_part 65536 f | y_part 1048576 f
  //            | routed 393216 f | wvacc_bf 32768 bf16
  float* ws          = (float*)d_ws;
  unsigned* bar      = (unsigned*)ws;
  float* ysum_part   = ws + 4096;
  float* y_part      = ysum_part + (size_t)G_ * CPG * 128;
  float* routed_part = y_part + (size_t)G_ * CPG * 2048;
  short* wvacc_bf    = (short*)(routed_part + (size_t)G_ * CPG * 768);

  hipMemsetAsync((void*)bar, 0, (size_t)G_ * 64 * sizeof(unsigned), stream);
  caps_mega3<<<dim3(G_ * CPG), dim3(512), 0, stream>>>(
      x, xv, Ws, Wv, bias, wvacc_bf, y_part, routed_part, ysum_part,
      caps, vecs, bar);
}